// Round 3
// baseline (9107.298 us; speedup 1.0000x reference)
//
#include <hip/hip_runtime.h>
#include <hip/hip_bf16.h>
#include <hip/hip_cooperative_groups.h>
#include <math.h>

namespace cg = cooperative_groups;

#define H_DIM 1024
#define W_DIM 512
#define VOC 32000
#define CAP_LEN 64
#define U_DIM 256
#define IMG_DIM 2048
#define XIN_DIM (IMG_DIM + U_DIM)   // 2304
#define SOS 31998
#define NBLK_LOGITS 512              // fallback-path partial blocks
#define CO_NBLK 256
#define CO_NTHR 512

// ---------------- ws layout ----------------
// floats: h0 @ 0, h1 @ 1024, c0 @ 2048, c1 @ 3072, xin @ 4096, x0 @ 6400
// bytes:  partial @ 27904 (512 u64; coop path uses first 256)
// bytes:  WP16 @ 1 MiB (32000*1024 bf16 = 65.5 MB)

__device__ __forceinline__ float wave_reduce_sum(float v) {
    #pragma unroll
    for (int off = 32; off > 0; off >>= 1)
        v += __shfl_xor(v, off, 64);
    return v;
}

__device__ __forceinline__ unsigned long long umax64(unsigned long long a, unsigned long long b) {
    return a > b ? a : b;
}

__device__ __forceinline__ unsigned short f2bf_rne(float f) {
    unsigned u = __float_as_uint(f);
    unsigned rounding = 0x7FFFu + ((u >> 16) & 1u);
    return (unsigned short)((u + rounding) >> 16);
}
__device__ __forceinline__ float bflo(unsigned u) { return __uint_as_float(u << 16); }
__device__ __forceinline__ float bfhi(unsigned u) { return __uint_as_float(u & 0xFFFF0000u); }

// one LSTM gate-row dot: W_ih_row (512) . x + W_hh_row (1024) . h  (bit-identical to R2)
__device__ __forceinline__ float lstm_row_dot(const float* __restrict__ wi,
                                              const float* __restrict__ wh,
                                              const float* __restrict__ x,
                                              const float* __restrict__ h_in,
                                              int lane) {
    float acc = 0.f;
    #pragma unroll
    for (int k = 0; k < 2; ++k) {
        int col = 4 * lane + 256 * k;
        float4 w4 = *reinterpret_cast<const float4*>(wi + col);
        float4 v4 = *reinterpret_cast<const float4*>(x  + col);
        acc += w4.x * v4.x + w4.y * v4.y + w4.z * v4.z + w4.w * v4.w;
    }
    #pragma unroll
    for (int k = 0; k < 4; ++k) {
        int col = 4 * lane + 256 * k;
        float4 w4 = *reinterpret_cast<const float4*>(wh   + col);
        float4 v4 = *reinterpret_cast<const float4*>(h_in + col);
        acc += w4.x * v4.x + w4.y * v4.y + w4.z * v4.z + w4.w * v4.w;
    }
    return wave_reduce_sum(acc);
}

// WP_w f32 -> bf16 (RNE), 8 elems/thread
__global__ void k_cvt_wp(const float* __restrict__ src, ushort* __restrict__ dst) {
    int i = blockIdx.x * blockDim.x + threadIdx.x;   // i < 4096000
    const float4 a = reinterpret_cast<const float4*>(src)[2 * i];
    const float4 b = reinterpret_cast<const float4*>(src)[2 * i + 1];
    union { ushort s[8]; uint4 v; } u;
    u.s[0] = f2bf_rne(a.x); u.s[1] = f2bf_rne(a.y);
    u.s[2] = f2bf_rne(a.z); u.s[3] = f2bf_rne(a.w);
    u.s[4] = f2bf_rne(b.x); u.s[5] = f2bf_rne(b.y);
    u.s[6] = f2bf_rne(b.z); u.s[7] = f2bf_rne(b.w);
    reinterpret_cast<uint4*>(dst)[i] = u.v;
}

// ======================= persistent cooperative decoder =======================
struct CoopParams {
    const float *img, *wei_user, *WI_w, *WI_b, *WP_w, *WP_b,
                *W_ih, *W_hh, *b_ih, *b_hh, *word_emb;
    const int* uid;
    const ushort* WP16;
    float* wsf;
    unsigned long long* partial;   // 256 entries
    float* out_hid;                // [64][1024]
    float* out_cap;                // [64]
    int use_bf16;
};

__global__ void __launch_bounds__(CO_NTHR, 1) k_decode(CoopParams p) {
    cg::grid_group grid = cg::this_grid();
    const int tid  = threadIdx.x;
    const int bid  = blockIdx.x;
    const int wv   = tid >> 6;
    const int lane = tid & 63;

    float* h0 = p.wsf;
    float* h1 = p.wsf + 1024;
    float* c0 = p.wsf + 2048;
    float* c1 = p.wsf + 3072;
    float* xin = p.wsf + 4096;
    float* x0  = p.wsf + 6400;

    __shared__ unsigned long long red[256];
    __shared__ float gsm[4][4];                 // [jslot][gate]
    __shared__ unsigned long long bsm[8];

    // ---- init: zero h/c buffers, build xin = concat(img, user_emb) ----
    {
        int g = bid * CO_NTHR + tid;
        if (g < 4096) p.wsf[g] = 0.f;
        if (g < XIN_DIM)
            xin[g] = (g < IMG_DIM) ? p.img[g]
                                   : p.wei_user[(size_t)p.uid[0] * U_DIM + (g - IMG_DIM)];
    }
    __threadfence();
    grid.sync();

    // ---- x0 = WI_w @ xin + WI_b (waves 0..511, one row each) ----
    {
        int gw = bid * 8 + wv;
        if (gw < 512) {
            const float* wr = p.WI_w + (size_t)gw * XIN_DIM;
            float acc = 0.f;
            #pragma unroll
            for (int k = 0; k < 9; ++k) {
                int col = 4 * lane + 256 * k;
                float4 w4 = *reinterpret_cast<const float4*>(wr  + col);
                float4 v4 = *reinterpret_cast<const float4*>(xin + col);
                acc += w4.x * v4.x + w4.y * v4.y + w4.z * v4.z + w4.w * v4.w;
            }
            acc = wave_reduce_sum(acc);
            if (lane == 0) x0[gw] = acc + p.WI_b[gw];
        }
    }
    __threadfence();
    grid.sync();

    // block reduces the 256 per-block logits partials -> winning token id
    auto reduce_wid = [&]() -> int {
        if (tid < 256) red[tid] = p.partial[tid];
        __syncthreads();
        #pragma unroll
        for (int s = 128; s >= 1; s >>= 1) {
            if (tid < s) red[tid] = umax64(red[tid], red[tid + s]);
            __syncthreads();
        }
        return (int)(0xFFFFFFFFu - (unsigned)(red[0] & 0xFFFFFFFFull));
    };

    // one LSTM step: block owns j = bid*4 + (wv&3); wave pair (wv<4 / wv>=4)
    // computes gates {i,f} / {g,o}; combine via LDS.
    auto lstm_phase = [&](const float* x, const float* h_in, const float* c_in,
                          float* h_out, float* c_out, float* out_hid) {
        const int jslot = wv & 3;
        const int j = bid * 4 + jslot;
        const int g0 = (wv < 4) ? 0 : 2;
        int row = g0 * H_DIM + j;
        float ga = lstm_row_dot(p.W_ih + (size_t)row * W_DIM,
                                p.W_hh + (size_t)row * H_DIM, x, h_in, lane)
                 + p.b_ih[row] + p.b_hh[row];
        row = (g0 + 1) * H_DIM + j;
        float gb = lstm_row_dot(p.W_ih + (size_t)row * W_DIM,
                                p.W_hh + (size_t)row * H_DIM, x, h_in, lane)
                 + p.b_ih[row] + p.b_hh[row];
        if (lane == 0) { gsm[jslot][g0] = ga; gsm[jslot][g0 + 1] = gb; }
        __syncthreads();
        if (wv < 4 && lane == 0) {
            float gi_ = gsm[jslot][0], gf = gsm[jslot][1];
            float gg  = gsm[jslot][2], go = gsm[jslot][3];
            float ig = 1.f / (1.f + expf(-gi_));
            float fg = 1.f / (1.f + expf(-gf));
            float g_ = tanhf(gg);
            float og = 1.f / (1.f + expf(-go));
            float cn = fg * c_in[j] + ig * g_;
            float hn = og * tanhf(cn);
            c_out[j] = cn;
            h_out[j] = hn;
            if (out_hid) out_hid[j] = hn;
        }
        __syncthreads();
    };

    auto logits_bf16_phase = [&](const float* h) {
        float4 h0a = *reinterpret_cast<const float4*>(h + 8 * lane);
        float4 h0b = *reinterpret_cast<const float4*>(h + 8 * lane + 4);
        float4 h1a = *reinterpret_cast<const float4*>(h + 8 * lane + 512);
        float4 h1b = *reinterpret_cast<const float4*>(h + 8 * lane + 516);
        unsigned long long best = 0ull;
        for (int row = bid * 8 + wv; row < VOC; row += 2048) {
            const uint4* wr = reinterpret_cast<const uint4*>(p.WP16 + (size_t)row * H_DIM);
            uint4 w0 = wr[lane];
            uint4 w1 = wr[lane + 64];
            float acc;
            acc  = bflo(w0.x) * h0a.x + bfhi(w0.x) * h0a.y;
            acc += bflo(w0.y) * h0a.z + bfhi(w0.y) * h0a.w;
            acc += bflo(w0.z) * h0b.x + bfhi(w0.z) * h0b.y;
            acc += bflo(w0.w) * h0b.z + bfhi(w0.w) * h0b.w;
            acc += bflo(w1.x) * h1a.x + bfhi(w1.x) * h1a.y;
            acc += bflo(w1.y) * h1a.z + bfhi(w1.y) * h1a.w;
            acc += bflo(w1.z) * h1b.x + bfhi(w1.z) * h1b.y;
            acc += bflo(w1.w) * h1b.z + bfhi(w1.w) * h1b.w;
            acc = wave_reduce_sum(acc);
            float logit = acc + p.WP_b[row];
            unsigned int ub = __float_as_uint(logit);
            ub = (ub & 0x80000000u) ? ~ub : (ub | 0x80000000u);
            unsigned long long pk = ((unsigned long long)ub << 32)
                                  | (unsigned long long)(0xFFFFFFFFu - (unsigned)row);
            best = umax64(best, pk);
        }
        if (lane == 0) bsm[wv] = best;
        __syncthreads();
        if (tid == 0) {
            unsigned long long m = bsm[0];
            #pragma unroll
            for (int i = 1; i < 8; ++i) m = umax64(m, bsm[i]);
            p.partial[bid] = m;
        }
        __syncthreads();
    };

    auto logits_f32_phase = [&](const float* h) {
        unsigned long long best = 0ull;
        for (int row = bid * 8 + wv; row < VOC; row += 2048) {
            const float* wr = p.WP_w + (size_t)row * H_DIM;
            float acc = 0.f;
            #pragma unroll
            for (int k = 0; k < 4; ++k) {
                int col = 4 * lane + 256 * k;
                float4 w4 = *reinterpret_cast<const float4*>(wr + col);
                float4 v4 = *reinterpret_cast<const float4*>(h  + col);
                acc += w4.x * v4.x + w4.y * v4.y + w4.z * v4.z + w4.w * v4.w;
            }
            acc = wave_reduce_sum(acc);
            float logit = acc + p.WP_b[row];
            unsigned int ub = __float_as_uint(logit);
            ub = (ub & 0x80000000u) ? ~ub : (ub | 0x80000000u);
            unsigned long long pk = ((unsigned long long)ub << 32)
                                  | (unsigned long long)(0xFFFFFFFFu - (unsigned)row);
            best = umax64(best, pk);
        }
        if (lane == 0) bsm[wv] = best;
        __syncthreads();
        if (tid == 0) {
            unsigned long long m = bsm[0];
            #pragma unroll
            for (int i = 1; i < 8; ++i) m = umax64(m, bsm[i]);
            p.partial[bid] = m;
        }
        __syncthreads();
    };

    // ---- prime step: h=c=0 -> buf1 ----
    lstm_phase(x0, h0, c0, h1, c1, nullptr);
    __threadfence();
    grid.sync();

    for (int t = 0; t < CAP_LEN; ++t) {
        const float* hi = (t & 1) ? h0 : h1;
        const float* ci = (t & 1) ? c0 : c1;
        float* ho = (t & 1) ? h1 : h0;
        float* co = (t & 1) ? c1 : c0;
        const float* x;
        if (t == 0) {
            x = p.word_emb + (size_t)SOS * W_DIM;
        } else {
            int wid = reduce_wid();
            if (bid == 0 && tid == 0) p.out_cap[t - 1] = (float)wid;
            x = p.word_emb + (size_t)wid * W_DIM;
        }
        lstm_phase(x, hi, ci, ho, co, p.out_hid + (size_t)t * H_DIM);
        __threadfence();
        grid.sync();
        if (p.use_bf16) logits_bf16_phase(ho);
        else            logits_f32_phase(ho);
        __threadfence();
        grid.sync();
    }
    if (bid == 0) {
        int wid = reduce_wid();
        if (tid == 0) p.out_cap[CAP_LEN - 1] = (float)wid;
    }
}

// ======================= fallback path (R2 kernels) =======================
__global__ void k_init(const float* __restrict__ img, const int* __restrict__ uid,
                       const float* __restrict__ wei_user, float* __restrict__ wsf) {
    int i = blockIdx.x * blockDim.x + threadIdx.x;
    if (i < 4096) wsf[i] = 0.f;
    if (i < XIN_DIM) {
        float v = (i < IMG_DIM) ? img[i]
                                : wei_user[(size_t)uid[0] * U_DIM + (i - IMG_DIM)];
        wsf[4096 + i] = v;
    }
}

__global__ void k_x0(const float* __restrict__ WI_w, const float* __restrict__ WI_b,
                     const float* __restrict__ xin, float* __restrict__ x0) {
    int wave = threadIdx.x >> 6;
    int lane = threadIdx.x & 63;
    int row  = blockIdx.x * 4 + wave;
    const float* wr = WI_w + (size_t)row * XIN_DIM;
    float acc = 0.f;
    #pragma unroll
    for (int k = 0; k < 9; ++k) {
        int col = 4 * lane + 256 * k;
        float4 w4 = *reinterpret_cast<const float4*>(wr  + col);
        float4 v4 = *reinterpret_cast<const float4*>(xin + col);
        acc += w4.x * v4.x + w4.y * v4.y + w4.z * v4.z + w4.w * v4.w;
    }
    acc = wave_reduce_sum(acc);
    if (lane == 0) x0[row] = acc + WI_b[row];
}

__global__ void k_lstm(int t,
                       const float* __restrict__ W_ih, const float* __restrict__ W_hh,
                       const float* __restrict__ b_ih, const float* __restrict__ b_hh,
                       const float* __restrict__ word_emb, const float* __restrict__ x0,
                       const unsigned long long* __restrict__ partial,
                       float* __restrict__ out_cap,
                       const float* __restrict__ h_in, const float* __restrict__ c_in,
                       float* __restrict__ h_out, float* __restrict__ c_out,
                       float* __restrict__ out_hid) {
    __shared__ unsigned long long red[256];
    int tid  = threadIdx.x;
    int wave = tid >> 6;
    int lane = tid & 63;
    int j = blockIdx.x * 4 + wave;

    const float* x;
    if (t < 0) {
        x = x0;
    } else if (t == 0) {
        x = word_emb + (size_t)SOS * W_DIM;
    } else {
        red[tid] = umax64(partial[tid], partial[tid + 256]);
        __syncthreads();
        #pragma unroll
        for (int s = 128; s >= 1; s >>= 1) {
            if (tid < s) red[tid] = umax64(red[tid], red[tid + s]);
            __syncthreads();
        }
        int wid = (int)(0xFFFFFFFFu - (unsigned)(red[0] & 0xFFFFFFFFull));
        if (blockIdx.x == 0 && tid == 0) out_cap[t - 1] = (float)wid;
        x = word_emb + (size_t)wid * W_DIM;
    }

    float g[4];
    #pragma unroll
    for (int gi = 0; gi < 4; ++gi) {
        int row = gi * H_DIM + j;
        float acc = lstm_row_dot(W_ih + (size_t)row * W_DIM,
                                 W_hh + (size_t)row * H_DIM, x, h_in, lane);
        g[gi] = acc + b_ih[row] + b_hh[row];
    }
    if (lane == 0) {
        float ig = 1.f / (1.f + expf(-g[0]));
        float fg = 1.f / (1.f + expf(-g[1]));
        float gg = tanhf(g[2]);
        float og = 1.f / (1.f + expf(-g[3]));
        float cn = fg * c_in[j] + ig * gg;
        float hn = og * tanhf(cn);
        c_out[j] = cn;
        h_out[j] = hn;
        if (out_hid) out_hid[j] = hn;
    }
}

__global__ void k_logits_bf16(const ushort* __restrict__ WP16,
                              const float* __restrict__ WP_b,
                              const float* __restrict__ h,
                              unsigned long long* __restrict__ partial) {
    int wave = threadIdx.x >> 6;
    int lane = threadIdx.x & 63;
    int wv = blockIdx.x * 4 + wave;
    float4 h0a = *reinterpret_cast<const float4*>(h + 8 * lane);
    float4 h0b = *reinterpret_cast<const float4*>(h + 8 * lane + 4);
    float4 h1a = *reinterpret_cast<const float4*>(h + 8 * lane + 512);
    float4 h1b = *reinterpret_cast<const float4*>(h + 8 * lane + 516);
    unsigned long long best = 0ull;
    for (int row = wv; row < VOC; row += NBLK_LOGITS * 4) {
        const uint4* wr = reinterpret_cast<const uint4*>(WP16 + (size_t)row * H_DIM);
        uint4 w0 = wr[lane];
        uint4 w1 = wr[lane + 64];
        float acc;
        acc  = bflo(w0.x) * h0a.x + bfhi(w0.x) * h0a.y;
        acc += bflo(w0.y) * h0a.z + bfhi(w0.y) * h0a.w;
        acc += bflo(w0.z) * h0b.x + bfhi(w0.z) * h0b.y;
        acc += bflo(w0.w) * h0b.z + bfhi(w0.w) * h0b.w;
        acc += bflo(w1.x) * h1a.x + bfhi(w1.x) * h1a.y;
        acc += bflo(w1.y) * h1a.z + bfhi(w1.y) * h1a.w;
        acc += bflo(w1.z) * h1b.x + bfhi(w1.z) * h1b.y;
        acc += bflo(w1.w) * h1b.z + bfhi(w1.w) * h1b.w;
        acc = wave_reduce_sum(acc);
        float logit = acc + WP_b[row];
        unsigned int ub = __float_as_uint(logit);
        ub = (ub & 0x80000000u) ? ~ub : (ub | 0x80000000u);
        unsigned long long pk = ((unsigned long long)ub << 32)
                              | (unsigned long long)(0xFFFFFFFFu - (unsigned)row);
        best = umax64(best, pk);
    }
    __shared__ unsigned long long sm[4];
    if (lane == 0) sm[wave] = best;
    __syncthreads();
    if (threadIdx.x == 0)
        partial[blockIdx.x] = umax64(umax64(sm[0], sm[1]), umax64(sm[2], sm[3]));
}

__global__ void k_argmax_final(const unsigned long long* __restrict__ partial,
                               float* __restrict__ out_cap) {
    __shared__ unsigned long long sm[256];
    int tid = threadIdx.x;
    sm[tid] = umax64(partial[tid], partial[tid + 256]);
    __syncthreads();
    for (int s = 128; s > 0; s >>= 1) {
        if (tid < s) sm[tid] = umax64(sm[tid], sm[tid + s]);
        __syncthreads();
    }
    if (tid == 0) {
        int row = (int)(0xFFFFFFFFu - (unsigned)(sm[0] & 0xFFFFFFFFull));
        out_cap[CAP_LEN - 1] = (float)row;
    }
}

extern "C" void kernel_launch(void* const* d_in, const int* in_sizes, int n_in,
                              void* d_out, int out_size, void* d_ws, size_t ws_size,
                              hipStream_t stream) {
    const float* img_feat = (const float*)d_in[0];
    const int*   uid      = (const int*)  d_in[1];
    const float* wei_user = (const float*)d_in[2];
    const float* WI_w     = (const float*)d_in[3];
    const float* WI_b     = (const float*)d_in[4];
    const float* WP_w     = (const float*)d_in[5];
    const float* WP_b     = (const float*)d_in[6];
    const float* W_ih     = (const float*)d_in[7];
    const float* W_hh     = (const float*)d_in[8];
    const float* b_ih     = (const float*)d_in[9];
    const float* b_hh     = (const float*)d_in[10];
    const float* word_emb = (const float*)d_in[11];

    float* out = (float*)d_out;
    float* wsf = (float*)d_ws;
    unsigned long long* partial = (unsigned long long*)((char*)d_ws + 27904);
    ushort* WP16 = (ushort*)((char*)d_ws + (1 << 20));
    const size_t wp16_need = (size_t)(1u << 20) + (size_t)VOC * H_DIM * sizeof(ushort);
    const bool use_bf16 = ws_size >= wp16_need;

    float* out_cap = out + CAP_LEN * H_DIM;

    if (use_bf16)
        k_cvt_wp<<<16000, 256, 0, stream>>>(WP_w, WP16);

    CoopParams p;
    p.img = img_feat; p.wei_user = wei_user; p.WI_w = WI_w; p.WI_b = WI_b;
    p.WP_w = WP_w; p.WP_b = WP_b; p.W_ih = W_ih; p.W_hh = W_hh;
    p.b_ih = b_ih; p.b_hh = b_hh; p.word_emb = word_emb; p.uid = uid;
    p.WP16 = WP16; p.wsf = wsf; p.partial = partial;
    p.out_hid = out; p.out_cap = out_cap; p.use_bf16 = use_bf16 ? 1 : 0;

    void* args[] = { &p };
    hipError_t err = hipLaunchCooperativeKernel((const void*)k_decode,
                                                dim3(CO_NBLK), dim3(CO_NTHR),
                                                args, 0, stream);
    if (err != hipSuccess) {
        (void)hipGetLastError();   // clear sticky error, use multi-launch path
        float* h0 = wsf;
        float* h1 = wsf + 1024;
        float* c0 = wsf + 2048;
        float* c1 = wsf + 3072;
        float* xin = wsf + 4096;
        float* x0  = wsf + 6400;
        k_init<<<16, 256, 0, stream>>>(img_feat, uid, wei_user, wsf);
        k_x0<<<128, 256, 0, stream>>>(WI_w, WI_b, xin, x0);
        k_lstm<<<256, 256, 0, stream>>>(-1, W_ih, W_hh, b_ih, b_hh, word_emb, x0,
                                        partial, out_cap, h0, c0, h1, c1, nullptr);
        for (int t = 0; t < CAP_LEN; ++t) {
            const float* hi = (t & 1) ? h0 : h1;
            const float* ci = (t & 1) ? c0 : c1;
            float* ho = (t & 1) ? h1 : h0;
            float* co = (t & 1) ? c1 : c0;
            k_lstm<<<256, 256, 0, stream>>>(t, W_ih, W_hh, b_ih, b_hh, word_emb, x0,
                                            partial, out_cap, hi, ci, ho, co,
                                            out + (size_t)t * H_DIM);
            k_logits_bf16<<<NBLK_LOGITS, 256, 0, stream>>>(WP16, WP_b, ho, partial);
        }
        k_argmax_final<<<1, 256, 0, stream>>>(partial, out_cap);
    }
}

// Round 4
// 1531.030 us; speedup vs baseline: 5.9485x; 5.9485x over previous
//
#include <hip/hip_runtime.h>
#include <hip/hip_bf16.h>
#include <hip/hip_cooperative_groups.h>
#include <math.h>

#define H_DIM 1024
#define W_DIM 512
#define VOC 32000
#define CAP_LEN 64
#define U_DIM 256
#define IMG_DIM 2048
#define XIN_DIM (IMG_DIM + U_DIM)   // 2304
#define SOS 31998
#define NBLK_LOGITS 512              // fallback-path partial blocks
#define CO_NBLK 256
#define CO_NTHR 512
#define SCOPE_AGENT __HIP_MEMORY_SCOPE_AGENT

// ---------------- ws layout (bytes) ----------------
// 0:    bar_cnt (u32)      128:  bar_gen (u32)
// 1024: h_glob[1024] f32   (coherent h publish buffer)
// 5120: x0[512] f32
// 8192: partial[256] u64
// 16384: fallback-path floats (h0,h1,c0,c1,xin,x0)  [R2 layout, offset by 16KB]
// 1 MiB: WP16 (32000*1024 bf16)

__device__ __forceinline__ float wave_reduce_sum(float v) {
    #pragma unroll
    for (int off = 32; off > 0; off >>= 1)
        v += __shfl_xor(v, off, 64);
    return v;
}

__device__ __forceinline__ unsigned long long umax64(unsigned long long a, unsigned long long b) {
    return a > b ? a : b;
}

__device__ __forceinline__ unsigned short f2bf_rne(float f) {
    unsigned u = __float_as_uint(f);
    unsigned rounding = 0x7FFFu + ((u >> 16) & 1u);
    return (unsigned short)((u + rounding) >> 16);
}
__device__ __forceinline__ float bflo(unsigned u) { return __uint_as_float(u << 16); }
__device__ __forceinline__ float bfhi(unsigned u) { return __uint_as_float(u & 0xFFFF0000u); }

// coherent (L2-bypassing, MALL-served) relaxed accesses for cross-block data
__device__ __forceinline__ float ld_coh(const float* p) {
    return __hip_atomic_load(p, __ATOMIC_RELAXED, SCOPE_AGENT);
}
__device__ __forceinline__ void st_coh(float* p, float v) {
    __hip_atomic_store(p, v, __ATOMIC_RELAXED, SCOPE_AGENT);
}
__device__ __forceinline__ unsigned long long ld_coh64(const unsigned long long* p) {
    return __hip_atomic_load(p, __ATOMIC_RELAXED, SCOPE_AGENT);
}
__device__ __forceinline__ void st_coh64(unsigned long long* p, unsigned long long v) {
    __hip_atomic_store(p, v, __ATOMIC_RELAXED, SCOPE_AGENT);
}

// generation barrier: NO acquire fence (no buffer_inv -> L2 stays hot).
// __syncthreads drains each wave's vmcnt (coherent stores ack'd at MALL)
// before thread 0's arrival fetch_add.
__device__ __forceinline__ void gbar(unsigned* cnt, unsigned* gen, unsigned target) {
    __syncthreads();
    if (threadIdx.x == 0) {
        unsigned old = __hip_atomic_fetch_add(cnt, 1u, __ATOMIC_RELAXED, SCOPE_AGENT);
        if (old == CO_NBLK - 1) {
            __hip_atomic_store(cnt, 0u, __ATOMIC_RELAXED, SCOPE_AGENT);
            __hip_atomic_store(gen, target, __ATOMIC_RELEASE, SCOPE_AGENT);
        } else {
            while (__hip_atomic_load(gen, __ATOMIC_RELAXED, SCOPE_AGENT) < target)
                __builtin_amdgcn_s_sleep(2);
        }
    }
    __syncthreads();
    asm volatile("" ::: "memory");
}

// one LSTM gate-row dot (x, h from LDS; weights cached): bit-identical math to R2
__device__ __forceinline__ float lstm_row_dot(const float* __restrict__ wi,
                                              const float* __restrict__ wh,
                                              const float* __restrict__ x,
                                              const float* __restrict__ h_in,
                                              int lane) {
    float acc = 0.f;
    #pragma unroll
    for (int k = 0; k < 2; ++k) {
        int col = 4 * lane + 256 * k;
        float4 w4 = *reinterpret_cast<const float4*>(wi + col);
        float4 v4 = *reinterpret_cast<const float4*>(x  + col);
        acc += w4.x * v4.x + w4.y * v4.y + w4.z * v4.z + w4.w * v4.w;
    }
    #pragma unroll
    for (int k = 0; k < 4; ++k) {
        int col = 4 * lane + 256 * k;
        float4 w4 = *reinterpret_cast<const float4*>(wh   + col);
        float4 v4 = *reinterpret_cast<const float4*>(h_in + col);
        acc += w4.x * v4.x + w4.y * v4.y + w4.z * v4.z + w4.w * v4.w;
    }
    return wave_reduce_sum(acc);
}

// WP_w f32 -> bf16 (RNE), 8 elems/thread
__global__ void k_cvt_wp(const float* __restrict__ src, ushort* __restrict__ dst) {
    int i = blockIdx.x * blockDim.x + threadIdx.x;   // i < 4096000
    const float4 a = reinterpret_cast<const float4*>(src)[2 * i];
    const float4 b = reinterpret_cast<const float4*>(src)[2 * i + 1];
    union { ushort s[8]; uint4 v; } u;
    u.s[0] = f2bf_rne(a.x); u.s[1] = f2bf_rne(a.y);
    u.s[2] = f2bf_rne(a.z); u.s[3] = f2bf_rne(a.w);
    u.s[4] = f2bf_rne(b.x); u.s[5] = f2bf_rne(b.y);
    u.s[6] = f2bf_rne(b.z); u.s[7] = f2bf_rne(b.w);
    reinterpret_cast<uint4*>(dst)[i] = u.v;
}

__global__ void k_reset(unsigned* bar) {
    if (threadIdx.x < 64) bar[threadIdx.x] = 0u;   // cnt @0, gen @32 (u32 idx)
}

// ======================= persistent decoder =======================
struct CoopParams {
    const float *img, *wei_user, *WI_w, *WI_b, *WP_w, *WP_b,
                *W_ih, *W_hh, *b_ih, *b_hh, *word_emb;
    const int* uid;
    const ushort* WP16;
    unsigned* bar_cnt;             // ws byte 0
    unsigned* bar_gen;             // ws byte 128
    float* h_glob;                 // ws byte 1024 (1024 f32)
    float* x0_glob;                // ws byte 5120 (512 f32)
    unsigned long long* partial;   // ws byte 8192 (256 u64)
    float* out_hid;                // [64][1024]
    float* out_cap;                // [64]
    int use_bf16;
};

__global__ void __launch_bounds__(CO_NTHR, 1) k_decode(CoopParams p) {
    const int tid  = threadIdx.x;
    const int bid  = blockIdx.x;
    const int wv   = tid >> 6;
    const int lane = tid & 63;

    __shared__ float lds_xin[XIN_DIM];
    __shared__ float lds_x[W_DIM];
    __shared__ float lds_h[H_DIM];
    __shared__ unsigned long long lds_red[256];
    __shared__ float gsm[4][4];

    unsigned bgen = 0;
    float c_reg = 0.f;             // cell state for owner threads (wv<4, lane==0)

    // ---- per-block xin from read-only inputs (no cross-block traffic) ----
    for (int g = tid; g < XIN_DIM; g += CO_NTHR)
        lds_xin[g] = (g < IMG_DIM) ? p.img[g]
                                   : p.wei_user[(size_t)p.uid[0] * U_DIM + (g - IMG_DIM)];
    __syncthreads();

    // ---- distributed x0 = WI_w @ xin + WI_b (waves of blocks 0..63) ----
    {
        int gw = bid * 8 + wv;
        if (gw < 512) {
            const float* wr = p.WI_w + (size_t)gw * XIN_DIM;
            float acc = 0.f;
            #pragma unroll
            for (int k = 0; k < 9; ++k) {
                int col = 4 * lane + 256 * k;
                float4 w4 = *reinterpret_cast<const float4*>(wr + col);
                float4 v4 = *reinterpret_cast<const float4*>(&lds_xin[col]);
                acc += w4.x * v4.x + w4.y * v4.y + w4.z * v4.z + w4.w * v4.w;
            }
            acc = wave_reduce_sum(acc);
            if (lane == 0) st_coh(&p.x0_glob[gw], acc + p.WI_b[gw]);
        }
    }
    gbar(p.bar_cnt, p.bar_gen, ++bgen);

    // stage x0 -> lds_x; prime h = 0 -> lds_h
    if (tid < W_DIM) lds_x[tid] = ld_coh(&p.x0_glob[tid]);
    lds_h[tid] = 0.f;
    lds_h[tid + 512] = 0.f;
    __syncthreads();

    // LSTM phase: block owns j = bid*4 + (wv&3); wave pairs (wv<4 / wv>=4)
    // compute gates {i,f} / {g,o}; combine via LDS; c in registers.
    auto lstm_phase = [&](const float* x, float* out_hid) {
        const int jslot = wv & 3;
        const int j = bid * 4 + jslot;
        const int g0 = (wv < 4) ? 0 : 2;
        int row = g0 * H_DIM + j;
        float ga = lstm_row_dot(p.W_ih + (size_t)row * W_DIM,
                                p.W_hh + (size_t)row * H_DIM, x, lds_h, lane)
                 + p.b_ih[row] + p.b_hh[row];
        row = (g0 + 1) * H_DIM + j;
        float gb = lstm_row_dot(p.W_ih + (size_t)row * W_DIM,
                                p.W_hh + (size_t)row * H_DIM, x, lds_h, lane)
                 + p.b_ih[row] + p.b_hh[row];
        if (lane == 0) { gsm[jslot][g0] = ga; gsm[jslot][g0 + 1] = gb; }
        __syncthreads();
        if (wv < 4 && lane == 0) {
            float gi_ = gsm[jslot][0], gf = gsm[jslot][1];
            float gg  = gsm[jslot][2], go = gsm[jslot][3];
            float ig = 1.f / (1.f + expf(-gi_));
            float fg = 1.f / (1.f + expf(-gf));
            float g_ = tanhf(gg);
            float og = 1.f / (1.f + expf(-go));
            float cn = fg * c_reg + ig * g_;
            float hn = og * tanhf(cn);
            c_reg = cn;
            st_coh(&p.h_glob[j], hn);
            if (out_hid) out_hid[j] = hn;
        }
    };

    auto stage_h = [&]() {
        lds_h[tid]       = ld_coh(&p.h_glob[tid]);
        lds_h[tid + 512] = ld_coh(&p.h_glob[tid + 512]);
        __syncthreads();
    };

    auto logits_bf16_phase = [&]() {
        float4 h0a = *reinterpret_cast<const float4*>(&lds_h[8 * lane]);
        float4 h0b = *reinterpret_cast<const float4*>(&lds_h[8 * lane + 4]);
        float4 h1a = *reinterpret_cast<const float4*>(&lds_h[8 * lane + 512]);
        float4 h1b = *reinterpret_cast<const float4*>(&lds_h[8 * lane + 516]);
        unsigned long long best = 0ull;
        for (int row = bid * 8 + wv; row < VOC; row += 2048) {
            const uint4* wr = reinterpret_cast<const uint4*>(p.WP16 + (size_t)row * H_DIM);
            uint4 w0 = wr[lane];
            uint4 w1 = wr[lane + 64];
            float acc;
            acc  = bflo(w0.x) * h0a.x + bfhi(w0.x) * h0a.y;
            acc += bflo(w0.y) * h0a.z + bfhi(w0.y) * h0a.w;
            acc += bflo(w0.z) * h0b.x + bfhi(w0.z) * h0b.y;
            acc += bflo(w0.w) * h0b.z + bfhi(w0.w) * h0b.w;
            acc += bflo(w1.x) * h1a.x + bfhi(w1.x) * h1a.y;
            acc += bflo(w1.y) * h1a.z + bfhi(w1.y) * h1a.w;
            acc += bflo(w1.z) * h1b.x + bfhi(w1.z) * h1b.y;
            acc += bflo(w1.w) * h1b.z + bfhi(w1.w) * h1b.w;
            acc = wave_reduce_sum(acc);
            float logit = acc + p.WP_b[row];
            unsigned int ub = __float_as_uint(logit);
            ub = (ub & 0x80000000u) ? ~ub : (ub | 0x80000000u);
            unsigned long long pk = ((unsigned long long)ub << 32)
                                  | (unsigned long long)(0xFFFFFFFFu - (unsigned)row);
            best = umax64(best, pk);
        }
        if (lane == 0) lds_red[wv] = best;   // reuse red[0..7]
        __syncthreads();
        if (tid == 0) {
            unsigned long long m = lds_red[0];
            #pragma unroll
            for (int i = 1; i < 8; ++i) m = umax64(m, lds_red[i]);
            st_coh64(&p.partial[bid], m);
        }
    };

    auto logits_f32_phase = [&]() {
        unsigned long long best = 0ull;
        for (int row = bid * 8 + wv; row < VOC; row += 2048) {
            const float* wr = p.WP_w + (size_t)row * H_DIM;
            float acc = 0.f;
            #pragma unroll
            for (int k = 0; k < 4; ++k) {
                int col = 4 * lane + 256 * k;
                float4 w4 = *reinterpret_cast<const float4*>(wr + col);
                float4 v4 = *reinterpret_cast<const float4*>(&lds_h[col]);
                acc += w4.x * v4.x + w4.y * v4.y + w4.z * v4.z + w4.w * v4.w;
            }
            acc = wave_reduce_sum(acc);
            float logit = acc + p.WP_b[row];
            unsigned int ub = __float_as_uint(logit);
            ub = (ub & 0x80000000u) ? ~ub : (ub | 0x80000000u);
            unsigned long long pk = ((unsigned long long)ub << 32)
                                  | (unsigned long long)(0xFFFFFFFFu - (unsigned)row);
            best = umax64(best, pk);
        }
        if (lane == 0) lds_red[wv] = best;
        __syncthreads();
        if (tid == 0) {
            unsigned long long m = lds_red[0];
            #pragma unroll
            for (int i = 1; i < 8; ++i) m = umax64(m, lds_red[i]);
            st_coh64(&p.partial[bid], m);
        }
    };

    // all blocks reduce the 256 partials -> winning token id
    auto reduce_wid = [&]() -> int {
        if (tid < 256) lds_red[tid] = ld_coh64(&p.partial[tid]);
        __syncthreads();
        #pragma unroll
        for (int s = 128; s >= 1; s >>= 1) {
            if (tid < s) lds_red[tid] = umax64(lds_red[tid], lds_red[tid + s]);
            __syncthreads();
        }
        return (int)(0xFFFFFFFFu - (unsigned)(lds_red[0] & 0xFFFFFFFFull));
    };

    // ---- prime step (x = x0, h = 0) ----
    lstm_phase(lds_x, nullptr);
    gbar(p.bar_cnt, p.bar_gen, ++bgen);

    for (int t = 0; t < CAP_LEN; ++t) {
        stage_h();                              // h from prev LSTM publish
        if (t > 0) {
            int wid = reduce_wid();
            if (bid == 0 && tid == 0) p.out_cap[t - 1] = (float)wid;
            if (tid < W_DIM) lds_x[tid] = p.word_emb[(size_t)wid * W_DIM + tid];
        } else {
            if (tid < W_DIM) lds_x[tid] = p.word_emb[(size_t)SOS * W_DIM + tid];
        }
        __syncthreads();
        // logits for the *previous* h? No: logits need THIS step's h; order is
        // lstm first (uses staged h from prev step), then publish, then logits.
        lstm_phase(lds_x, p.out_hid + (size_t)t * H_DIM);
        gbar(p.bar_cnt, p.bar_gen, ++bgen);     // h(t) published
        stage_h();                              // fresh h(t)
        if (p.use_bf16) logits_bf16_phase();
        else            logits_f32_phase();
        gbar(p.bar_cnt, p.bar_gen, ++bgen);     // partials published
    }
    {
        int wid = reduce_wid();
        if (bid == 0 && tid == 0) p.out_cap[CAP_LEN - 1] = (float)wid;
    }
}

// ======================= fallback path (R2 kernels) =======================
__global__ void k_init(const float* __restrict__ img, const int* __restrict__ uid,
                       const float* __restrict__ wei_user, float* __restrict__ wsf) {
    int i = blockIdx.x * blockDim.x + threadIdx.x;
    if (i < 4096) wsf[i] = 0.f;
    if (i < XIN_DIM) {
        float v = (i < IMG_DIM) ? img[i]
                                : wei_user[(size_t)uid[0] * U_DIM + (i - IMG_DIM)];
        wsf[4096 + i] = v;
    }
}

__global__ void k_x0(const float* __restrict__ WI_w, const float* __restrict__ WI_b,
                     const float* __restrict__ xin, float* __restrict__ x0) {
    int wave = threadIdx.x >> 6;
    int lane = threadIdx.x & 63;
    int row  = blockIdx.x * 4 + wave;
    const float* wr = WI_w + (size_t)row * XIN_DIM;
    float acc = 0.f;
    #pragma unroll
    for (int k = 0; k < 9; ++k) {
        int col = 4 * lane + 256 * k;
        float4 w4 = *reinterpret_cast<const float4*>(wr  + col);
        float4 v4 = *reinterpret_cast<const float4*>(xin + col);
        acc += w4.x * v4.x + w4.y * v4.y + w4.z * v4.z + w4.w * v4.w;
    }
    acc = wave_reduce_sum(acc);
    if (lane == 0) x0[row] = acc + WI_b[row];
}

__global__ void k_lstm(int t,
                       const float* __restrict__ W_ih, const float* __restrict__ W_hh,
                       const float* __restrict__ b_ih, const float* __restrict__ b_hh,
                       const float* __restrict__ word_emb, const float* __restrict__ x0,
                       const unsigned long long* __restrict__ partial,
                       float* __restrict__ out_cap,
                       const float* __restrict__ h_in, const float* __restrict__ c_in,
                       float* __restrict__ h_out, float* __restrict__ c_out,
                       float* __restrict__ out_hid) {
    __shared__ unsigned long long red[256];
    int tid  = threadIdx.x;
    int wave = tid >> 6;
    int lane = tid & 63;
    int j = blockIdx.x * 4 + wave;

    const float* x;
    if (t < 0) {
        x = x0;
    } else if (t == 0) {
        x = word_emb + (size_t)SOS * W_DIM;
    } else {
        red[tid] = umax64(partial[tid], partial[tid + 256]);
        __syncthreads();
        #pragma unroll
        for (int s = 128; s >= 1; s >>= 1) {
            if (tid < s) red[tid] = umax64(red[tid], red[tid + s]);
            __syncthreads();
        }
        int wid = (int)(0xFFFFFFFFu - (unsigned)(red[0] & 0xFFFFFFFFull));
        if (blockIdx.x == 0 && tid == 0) out_cap[t - 1] = (float)wid;
        x = word_emb + (size_t)wid * W_DIM;
    }

    float g[4];
    #pragma unroll
    for (int gi = 0; gi < 4; ++gi) {
        int row = gi * H_DIM + j;
        float acc = lstm_row_dot(W_ih + (size_t)row * W_DIM,
                                 W_hh + (size_t)row * H_DIM, x, h_in, lane);
        g[gi] = acc + b_ih[row] + b_hh[row];
    }
    if (lane == 0) {
        float ig = 1.f / (1.f + expf(-g[0]));
        float fg = 1.f / (1.f + expf(-g[1]));
        float gg = tanhf(g[2]);
        float og = 1.f / (1.f + expf(-g[3]));
        float cn = fg * c_in[j] + ig * gg;
        float hn = og * tanhf(cn);
        c_out[j] = cn;
        h_out[j] = hn;
        if (out_hid) out_hid[j] = hn;
    }
}

__global__ void k_logits_bf16(const ushort* __restrict__ WP16,
                              const float* __restrict__ WP_b,
                              const float* __restrict__ h,
                              unsigned long long* __restrict__ partial) {
    int wave = threadIdx.x >> 6;
    int lane = threadIdx.x & 63;
    int wv = blockIdx.x * 4 + wave;
    float4 h0a = *reinterpret_cast<const float4*>(h + 8 * lane);
    float4 h0b = *reinterpret_cast<const float4*>(h + 8 * lane + 4);
    float4 h1a = *reinterpret_cast<const float4*>(h + 8 * lane + 512);
    float4 h1b = *reinterpret_cast<const float4*>(h + 8 * lane + 516);
    unsigned long long best = 0ull;
    for (int row = wv; row < VOC; row += NBLK_LOGITS * 4) {
        const uint4* wr = reinterpret_cast<const uint4*>(WP16 + (size_t)row * H_DIM);
        uint4 w0 = wr[lane];
        uint4 w1 = wr[lane + 64];
        float acc;
        acc  = bflo(w0.x) * h0a.x + bfhi(w0.x) * h0a.y;
        acc += bflo(w0.y) * h0a.z + bfhi(w0.y) * h0a.w;
        acc += bflo(w0.z) * h0b.x + bfhi(w0.z) * h0b.y;
        acc += bflo(w0.w) * h0b.z + bfhi(w0.w) * h0b.w;
        acc += bflo(w1.x) * h1a.x + bfhi(w1.x) * h1a.y;
        acc += bflo(w1.y) * h1a.z + bfhi(w1.y) * h1a.w;
        acc += bflo(w1.z) * h1b.x + bfhi(w1.z) * h1b.y;
        acc += bflo(w1.w) * h1b.z + bfhi(w1.w) * h1b.w;
        acc = wave_reduce_sum(acc);
        float logit = acc + WP_b[row];
        unsigned int ub = __float_as_uint(logit);
        ub = (ub & 0x80000000u) ? ~ub : (ub | 0x80000000u);
        unsigned long long pk = ((unsigned long long)ub << 32)
                              | (unsigned long long)(0xFFFFFFFFu - (unsigned)row);
        best = umax64(best, pk);
    }
    __shared__ unsigned long long sm[4];
    if (lane == 0) sm[wave] = best;
    __syncthreads();
    if (threadIdx.x == 0)
        partial[blockIdx.x] = umax64(umax64(sm[0], sm[1]), umax64(sm[2], sm[3]));
}

__global__ void k_argmax_final(const unsigned long long* __restrict__ partial,
                               float* __restrict__ out_cap) {
    __shared__ unsigned long long sm[256];
    int tid = threadIdx.x;
    sm[tid] = umax64(partial[tid], partial[tid + 256]);
    __syncthreads();
    for (int s = 128; s > 0; s >>= 1) {
        if (tid < s) sm[tid] = umax64(sm[tid], sm[tid + s]);
        __syncthreads();
    }
    if (tid == 0) {
        int row = (int)(0xFFFFFFFFu - (unsigned)(sm[0] & 0xFFFFFFFFull));
        out_cap[CAP_LEN - 1] = (float)row;
    }
}

extern "C" void kernel_launch(void* const* d_in, const int* in_sizes, int n_in,
                              void* d_out, int out_size, void* d_ws, size_t ws_size,
                              hipStream_t stream) {
    const float* img_feat = (const float*)d_in[0];
    const int*   uid      = (const int*)  d_in[1];
    const float* wei_user = (const float*)d_in[2];
    const float* WI_w     = (const float*)d_in[3];
    const float* WI_b     = (const float*)d_in[4];
    const float* WP_w     = (const float*)d_in[5];
    const float* WP_b     = (const float*)d_in[6];
    const float* W_ih     = (const float*)d_in[7];
    const float* W_hh     = (const float*)d_in[8];
    const float* b_ih     = (const float*)d_in[9];
    const float* b_hh     = (const float*)d_in[10];
    const float* word_emb = (const float*)d_in[11];

    float* out = (float*)d_out;
    float* out_cap = out + CAP_LEN * H_DIM;
    char* ws = (char*)d_ws;

    ushort* WP16 = (ushort*)(ws + (1 << 20));
    const size_t wp16_need = (size_t)(1u << 20) + (size_t)VOC * H_DIM * sizeof(ushort);
    const bool use_bf16 = ws_size >= wp16_need;

    if (use_bf16)
        k_cvt_wp<<<16000, 256, 0, stream>>>(WP_w, WP16);

    k_reset<<<1, 64, 0, stream>>>((unsigned*)ws);

    CoopParams p;
    p.img = img_feat; p.wei_user = wei_user; p.WI_w = WI_w; p.WI_b = WI_b;
    p.WP_w = WP_w; p.WP_b = WP_b; p.W_ih = W_ih; p.W_hh = W_hh;
    p.b_ih = b_ih; p.b_hh = b_hh; p.word_emb = word_emb; p.uid = uid;
    p.WP16 = WP16;
    p.bar_cnt = (unsigned*)ws;
    p.bar_gen = (unsigned*)(ws + 128);
    p.h_glob  = (float*)(ws + 1024);
    p.x0_glob = (float*)(ws + 5120);
    p.partial = (unsigned long long*)(ws + 8192);
    p.out_hid = out; p.out_cap = out_cap; p.use_bf16 = use_bf16 ? 1 : 0;

    void* args[] = { &p };
    hipError_t err = hipLaunchCooperativeKernel((const void*)k_decode,
                                                dim3(CO_NBLK), dim3(CO_NTHR),
                                                args, 0, stream);
    if (err != hipSuccess) {
        (void)hipGetLastError();   // clear sticky error, use multi-launch path
        float* wsf = (float*)(ws + 16384);
        float* h0 = wsf;
        float* h1 = wsf + 1024;
        float* c0 = wsf + 2048;
        float* c1 = wsf + 3072;
        float* xin = wsf + 4096;
        float* x0  = wsf + 6400;
        unsigned long long* partial = (unsigned long long*)(ws + 16384 + 27904);
        k_init<<<16, 256, 0, stream>>>(img_feat, uid, wei_user, wsf);
        k_x0<<<128, 256, 0, stream>>>(WI_w, WI_b, xin, x0);
        k_lstm<<<256, 256, 0, stream>>>(-1, W_ih, W_hh, b_ih, b_hh, word_emb, x0,
                                        partial, out_cap, h0, c0, h1, c1, nullptr);
        for (int t = 0; t < CAP_LEN; ++t) {
            const float* hi = (t & 1) ? h0 : h1;
            const float* ci = (t & 1) ? c0 : c1;
            float* ho = (t & 1) ? h1 : h0;
            float* co = (t & 1) ? c1 : c0;
            k_lstm<<<256, 256, 0, stream>>>(t, W_ih, W_hh, b_ih, b_hh, word_emb, x0,
                                            partial, out_cap, hi, ci, ho, co,
                                            out + (size_t)t * H_DIM);
            k_logits_bf16<<<NBLK_LOGITS, 256, 0, stream>>>(WP16, WP_b, ho, partial);
        }
        k_argmax_final<<<1, 256, 0, stream>>>(partial, out_cap);
    }
}

// Round 5
// 1490.124 us; speedup vs baseline: 6.1118x; 1.0275x over previous
//
#include <hip/hip_runtime.h>
#include <hip/hip_bf16.h>
#include <hip/hip_cooperative_groups.h>
#include <math.h>

#define H_DIM 1024
#define W_DIM 512
#define VOC 32000
#define CAP_LEN 64
#define U_DIM 256
#define IMG_DIM 2048
#define XIN_DIM (IMG_DIM + U_DIM)   // 2304
#define SOS 31998
#define NBLK_LOGITS 512              // fallback-path partial blocks
#define CO_NBLK 512
#define CO_NTHR 512
#define SCOPE_AGENT __HIP_MEMORY_SCOPE_AGENT

// ---------------- ws layout (bytes) ----------------
// 0..1023:  8 leaf counters (128B apart)
// 1024: root counter   1152: gen word
// 2048: h_glob[1024] f32    6144: x0_glob[512] f32    8192: partial[512] u64
// 16384: fallback-path floats (R2 layout)
// 1 MiB: WP16 (32000*1024 bf16)

__device__ __forceinline__ float wave_reduce_sum(float v) {
    #pragma unroll
    for (int off = 32; off > 0; off >>= 1)
        v += __shfl_xor(v, off, 64);
    return v;
}

__device__ __forceinline__ unsigned long long umax64(unsigned long long a, unsigned long long b) {
    return a > b ? a : b;
}

__device__ __forceinline__ unsigned short f2bf_rne(float f) {
    unsigned u = __float_as_uint(f);
    unsigned rounding = 0x7FFFu + ((u >> 16) & 1u);
    return (unsigned short)((u + rounding) >> 16);
}
__device__ __forceinline__ float bflo(unsigned u) { return __uint_as_float(u << 16); }
__device__ __forceinline__ float bfhi(unsigned u) { return __uint_as_float(u & 0xFFFF0000u); }

// coherent (MALL-served, L2-bypassing) relaxed accesses for cross-block data
__device__ __forceinline__ float ld_coh(const float* p) {
    return __hip_atomic_load(p, __ATOMIC_RELAXED, SCOPE_AGENT);
}
__device__ __forceinline__ void st_coh(float* p, float v) {
    __hip_atomic_store(p, v, __ATOMIC_RELAXED, SCOPE_AGENT);
}
__device__ __forceinline__ unsigned long long ld_coh64(const unsigned long long* p) {
    return __hip_atomic_load(p, __ATOMIC_RELAXED, SCOPE_AGENT);
}
__device__ __forceinline__ void st_coh64(unsigned long long* p, unsigned long long v) {
    __hip_atomic_store(p, v, __ATOMIC_RELAXED, SCOPE_AGENT);
}

// two-level generation barrier, no acquire fence (L2 stays hot).
// __syncthreads drains vmcnt (coherent stores ack'd at MALL) before arrival.
__device__ __forceinline__ void gbar(unsigned* leaf, unsigned* root, unsigned* gen,
                                     int bid, unsigned target) {
    __syncthreads();
    if (threadIdx.x == 0) {
        unsigned* lc = leaf + (bid & 7) * 32;   // 128B-separated cachelines
        unsigned old = __hip_atomic_fetch_add(lc, 1u, __ATOMIC_RELAXED, SCOPE_AGENT);
        if (old == (CO_NBLK / 8) - 1) {
            __hip_atomic_store(lc, 0u, __ATOMIC_RELAXED, SCOPE_AGENT);
            unsigned r = __hip_atomic_fetch_add(root, 1u, __ATOMIC_RELAXED, SCOPE_AGENT);
            if (r == 7u) {
                __hip_atomic_store(root, 0u, __ATOMIC_RELAXED, SCOPE_AGENT);
                __hip_atomic_store(gen, target, __ATOMIC_RELEASE, SCOPE_AGENT);
            }
        }
        while (__hip_atomic_load(gen, __ATOMIC_RELAXED, SCOPE_AGENT) < target)
            __builtin_amdgcn_s_sleep(2);
    }
    __syncthreads();
    asm volatile("" ::: "memory");
}

// one LSTM gate-row dot (x, h from LDS; weights cached): bit-identical math to R2
__device__ __forceinline__ float lstm_row_dot(const float* __restrict__ wi,
                                              const float* __restrict__ wh,
                                              const float* __restrict__ x,
                                              const float* __restrict__ h_in,
                                              int lane) {
    float acc = 0.f;
    #pragma unroll
    for (int k = 0; k < 2; ++k) {
        int col = 4 * lane + 256 * k;
        float4 w4 = *reinterpret_cast<const float4*>(wi + col);
        float4 v4 = *reinterpret_cast<const float4*>(x  + col);
        acc += w4.x * v4.x + w4.y * v4.y + w4.z * v4.z + w4.w * v4.w;
    }
    #pragma unroll
    for (int k = 0; k < 4; ++k) {
        int col = 4 * lane + 256 * k;
        float4 w4 = *reinterpret_cast<const float4*>(wh   + col);
        float4 v4 = *reinterpret_cast<const float4*>(h_in + col);
        acc += w4.x * v4.x + w4.y * v4.y + w4.z * v4.z + w4.w * v4.w;
    }
    return wave_reduce_sum(acc);
}

// WP_w f32 -> bf16 (RNE), 8 elems/thread
__global__ void k_cvt_wp(const float* __restrict__ src, ushort* __restrict__ dst) {
    int i = blockIdx.x * blockDim.x + threadIdx.x;   // i < 4096000
    const float4 a = reinterpret_cast<const float4*>(src)[2 * i];
    const float4 b = reinterpret_cast<const float4*>(src)[2 * i + 1];
    union { ushort s[8]; uint4 v; } u;
    u.s[0] = f2bf_rne(a.x); u.s[1] = f2bf_rne(a.y);
    u.s[2] = f2bf_rne(a.z); u.s[3] = f2bf_rne(a.w);
    u.s[4] = f2bf_rne(b.x); u.s[5] = f2bf_rne(b.y);
    u.s[6] = f2bf_rne(b.z); u.s[7] = f2bf_rne(b.w);
    reinterpret_cast<uint4*>(dst)[i] = u.v;
}

__global__ void k_reset(unsigned* bar) {
    bar[threadIdx.x] = 0u;    // 512 u32 = first 2KB (leaves, root, gen)
}

// ======================= persistent decoder =======================
struct CoopParams {
    const float *img, *wei_user, *WI_w, *WI_b, *WP_w, *WP_b,
                *W_ih, *W_hh, *b_ih, *b_hh, *word_emb;
    const int* uid;
    const ushort* WP16;
    unsigned* leaf;                // ws byte 0 (8 x 128B)
    unsigned* root;                // ws byte 1024
    unsigned* gen;                 // ws byte 1152
    float* h_glob;                 // ws byte 2048 (1024 f32)
    float* x0_glob;                // ws byte 6144 (512 f32)
    unsigned long long* partial;   // ws byte 8192 (512 u64)
    float* out_hid;                // [64][1024]
    float* out_cap;                // [64]
    int use_bf16;
};

__global__ void __launch_bounds__(CO_NTHR, 4) k_decode(CoopParams p) {
    const int tid  = threadIdx.x;
    const int bid  = blockIdx.x;
    const int wv   = tid >> 6;
    const int lane = tid & 63;

    __shared__ float lds_xin[XIN_DIM];
    __shared__ float lds_x[W_DIM];
    __shared__ float lds_h[H_DIM];
    __shared__ unsigned long long lds_red[CO_NBLK];
    __shared__ float gsm[2][4];

    unsigned bgen = 0;
    float c_reg = 0.f;             // cell state: threads (wv<2, lane==0) own j=bid*2+wv

    // ---- per-block xin (read-only inputs, cached loads) ----
    for (int g = tid; g < XIN_DIM; g += CO_NTHR)
        lds_xin[g] = (g < IMG_DIM) ? p.img[g]
                                   : p.wei_user[(size_t)p.uid[0] * U_DIM + (g - IMG_DIM)];
    __syncthreads();

    // ---- distributed x0 = WI_w @ xin + WI_b (waves of blocks 0..63) ----
    {
        int gw = bid * 8 + wv;
        if (gw < 512) {
            const float* wr = p.WI_w + (size_t)gw * XIN_DIM;
            float acc = 0.f;
            #pragma unroll
            for (int k = 0; k < 9; ++k) {
                int col = 4 * lane + 256 * k;
                float4 w4 = *reinterpret_cast<const float4*>(wr + col);
                float4 v4 = *reinterpret_cast<const float4*>(&lds_xin[col]);
                acc += w4.x * v4.x + w4.y * v4.y + w4.z * v4.z + w4.w * v4.w;
            }
            acc = wave_reduce_sum(acc);
            if (lane == 0) st_coh(&p.x0_glob[gw], acc + p.WI_b[gw]);
        }
    }
    gbar(p.leaf, p.root, p.gen, bid, ++bgen);

    // stage x0 -> lds_x; prime h = 0 -> lds_h
    if (tid < W_DIM) lds_x[tid] = ld_coh(&p.x0_glob[tid]);
    lds_h[tid] = 0.f;
    __syncthreads();

    // LSTM phase: block owns j in {bid*2, bid*2+1}; wave wv computes gate row
    // (gate = wv>>1, jslot = wv&1) -> 8 waves cover 2 j x 4 gates, 1 row/wave.
    auto lstm_phase = [&](const float* x, float* out_hid) {
        const int jslot = wv & 1;
        const int gate  = wv >> 1;
        const int j = bid * 2 + jslot;
        const int row = gate * H_DIM + j;
        float g = lstm_row_dot(p.W_ih + (size_t)row * W_DIM,
                               p.W_hh + (size_t)row * H_DIM, x, lds_h, lane)
                + p.b_ih[row] + p.b_hh[row];
        if (lane == 0) gsm[jslot][gate] = g;
        __syncthreads();
        if (wv < 2 && lane == 0) {
            float gi_ = gsm[wv][0], gf = gsm[wv][1];
            float gg  = gsm[wv][2], go = gsm[wv][3];
            int jj = bid * 2 + wv;
            float ig = 1.f / (1.f + expf(-gi_));
            float fg = 1.f / (1.f + expf(-gf));
            float g_ = tanhf(gg);
            float og = 1.f / (1.f + expf(-go));
            float cn = fg * c_reg + ig * g_;
            float hn = og * tanhf(cn);
            c_reg = cn;
            st_coh(&p.h_glob[jj], hn);
            if (out_hid) out_hid[jj] = hn;
        }
    };

    auto stage_h = [&]() {
        lds_h[tid]       = ld_coh(&p.h_glob[tid]);
        lds_h[tid + 512] = ld_coh(&p.h_glob[tid + 512]);
        __syncthreads();
    };

    auto logits_bf16_phase = [&]() {
        float4 h0a = *reinterpret_cast<const float4*>(&lds_h[8 * lane]);
        float4 h0b = *reinterpret_cast<const float4*>(&lds_h[8 * lane + 4]);
        float4 h1a = *reinterpret_cast<const float4*>(&lds_h[8 * lane + 512]);
        float4 h1b = *reinterpret_cast<const float4*>(&lds_h[8 * lane + 516]);
        const int gw = bid * 8 + wv;           // 4096 waves
        unsigned long long best = 0ull;
        #pragma unroll
        for (int k = 0; k < 8; ++k) {
            int row = gw + k * 4096;
            if (row < VOC) {
                const uint4* wr = reinterpret_cast<const uint4*>(p.WP16 + (size_t)row * H_DIM);
                uint4 w0 = wr[lane];
                uint4 w1 = wr[lane + 64];
                float acc;
                acc  = bflo(w0.x) * h0a.x + bfhi(w0.x) * h0a.y;
                acc += bflo(w0.y) * h0a.z + bfhi(w0.y) * h0a.w;
                acc += bflo(w0.z) * h0b.x + bfhi(w0.z) * h0b.y;
                acc += bflo(w0.w) * h0b.z + bfhi(w0.w) * h0b.w;
                acc += bflo(w1.x) * h1a.x + bfhi(w1.x) * h1a.y;
                acc += bflo(w1.y) * h1a.z + bfhi(w1.y) * h1a.w;
                acc += bflo(w1.z) * h1b.x + bfhi(w1.z) * h1b.y;
                acc += bflo(w1.w) * h1b.z + bfhi(w1.w) * h1b.w;
                acc = wave_reduce_sum(acc);
                float logit = acc + p.WP_b[row];
                unsigned int ub = __float_as_uint(logit);
                ub = (ub & 0x80000000u) ? ~ub : (ub | 0x80000000u);
                unsigned long long pk = ((unsigned long long)ub << 32)
                                      | (unsigned long long)(0xFFFFFFFFu - (unsigned)row);
                best = umax64(best, pk);
            }
        }
        if (lane == 0) lds_red[wv] = best;
        __syncthreads();
        if (tid == 0) {
            unsigned long long m = lds_red[0];
            #pragma unroll
            for (int i = 1; i < 8; ++i) m = umax64(m, lds_red[i]);
            st_coh64(&p.partial[bid], m);
        }
    };

    auto logits_f32_phase = [&]() {
        const int gw = bid * 8 + wv;
        unsigned long long best = 0ull;
        #pragma unroll
        for (int k = 0; k < 8; ++k) {
            int row = gw + k * 4096;
            if (row < VOC) {
                const float* wr = p.WP_w + (size_t)row * H_DIM;
                float acc = 0.f;
                #pragma unroll
                for (int kk = 0; kk < 4; ++kk) {
                    int col = 4 * lane + 256 * kk;
                    float4 w4 = *reinterpret_cast<const float4*>(wr + col);
                    float4 v4 = *reinterpret_cast<const float4*>(&lds_h[col]);
                    acc += w4.x * v4.x + w4.y * v4.y + w4.z * v4.z + w4.w * v4.w;
                }
                acc = wave_reduce_sum(acc);
                float logit = acc + p.WP_b[row];
                unsigned int ub = __float_as_uint(logit);
                ub = (ub & 0x80000000u) ? ~ub : (ub | 0x80000000u);
                unsigned long long pk = ((unsigned long long)ub << 32)
                                      | (unsigned long long)(0xFFFFFFFFu - (unsigned)row);
                best = umax64(best, pk);
            }
        }
        if (lane == 0) lds_red[wv] = best;
        __syncthreads();
        if (tid == 0) {
            unsigned long long m = lds_red[0];
            #pragma unroll
            for (int i = 1; i < 8; ++i) m = umax64(m, lds_red[i]);
            st_coh64(&p.partial[bid], m);
        }
    };

    // all blocks reduce the 512 partials -> winning token id
    auto reduce_wid = [&]() -> int {
        lds_red[tid] = ld_coh64(&p.partial[tid]);
        __syncthreads();
        #pragma unroll
        for (int s = 256; s >= 1; s >>= 1) {
            if (tid < s) lds_red[tid] = umax64(lds_red[tid], lds_red[tid + s]);
            __syncthreads();
        }
        return (int)(0xFFFFFFFFu - (unsigned)(lds_red[0] & 0xFFFFFFFFull));
    };

    // ---- prime step (x = x0, h = 0) ----
    lstm_phase(lds_x, nullptr);
    gbar(p.leaf, p.root, p.gen, bid, ++bgen);
    stage_h();                                 // h(prime)

    for (int t = 0; t < CAP_LEN; ++t) {
        if (t > 0) {
            int wid = reduce_wid();            // partials of step t-1
            if (bid == 0 && tid == 0) p.out_cap[t - 1] = (float)wid;
            if (tid < W_DIM) lds_x[tid] = p.word_emb[(size_t)wid * W_DIM + tid];
        } else {
            if (tid < W_DIM) lds_x[tid] = p.word_emb[(size_t)SOS * W_DIM + tid];
        }
        __syncthreads();
        lstm_phase(lds_x, p.out_hid + (size_t)t * H_DIM);   // reads lds_h (h(t-1))
        gbar(p.leaf, p.root, p.gen, bid, ++bgen);           // h(t) published
        stage_h();                                          // lds_h = h(t)
        if (p.use_bf16) logits_bf16_phase();
        else            logits_f32_phase();
        gbar(p.leaf, p.root, p.gen, bid, ++bgen);           // partials published
    }
    {
        int wid = reduce_wid();
        if (bid == 0 && tid == 0) p.out_cap[CAP_LEN - 1] = (float)wid;
    }
}

// ======================= fallback path (R2 kernels) =======================
__global__ void k_init(const float* __restrict__ img, const int* __restrict__ uid,
                       const float* __restrict__ wei_user, float* __restrict__ wsf) {
    int i = blockIdx.x * blockDim.x + threadIdx.x;
    if (i < 4096) wsf[i] = 0.f;
    if (i < XIN_DIM) {
        float v = (i < IMG_DIM) ? img[i]
                                : wei_user[(size_t)uid[0] * U_DIM + (i - IMG_DIM)];
        wsf[4096 + i] = v;
    }
}

__global__ void k_x0(const float* __restrict__ WI_w, const float* __restrict__ WI_b,
                     const float* __restrict__ xin, float* __restrict__ x0) {
    int wave = threadIdx.x >> 6;
    int lane = threadIdx.x & 63;
    int row  = blockIdx.x * 4 + wave;
    const float* wr = WI_w + (size_t)row * XIN_DIM;
    float acc = 0.f;
    #pragma unroll
    for (int k = 0; k < 9; ++k) {
        int col = 4 * lane + 256 * k;
        float4 w4 = *reinterpret_cast<const float4*>(wr  + col);
        float4 v4 = *reinterpret_cast<const float4*>(xin + col);
        acc += w4.x * v4.x + w4.y * v4.y + w4.z * v4.z + w4.w * v4.w;
    }
    acc = wave_reduce_sum(acc);
    if (lane == 0) x0[row] = acc + WI_b[row];
}

__global__ void k_lstm(int t,
                       const float* __restrict__ W_ih, const float* __restrict__ W_hh,
                       const float* __restrict__ b_ih, const float* __restrict__ b_hh,
                       const float* __restrict__ word_emb, const float* __restrict__ x0,
                       const unsigned long long* __restrict__ partial,
                       float* __restrict__ out_cap,
                       const float* __restrict__ h_in, const float* __restrict__ c_in,
                       float* __restrict__ h_out, float* __restrict__ c_out,
                       float* __restrict__ out_hid) {
    __shared__ unsigned long long red[256];
    int tid  = threadIdx.x;
    int wave = tid >> 6;
    int lane = tid & 63;
    int j = blockIdx.x * 4 + wave;

    const float* x;
    if (t < 0) {
        x = x0;
    } else if (t == 0) {
        x = word_emb + (size_t)SOS * W_DIM;
    } else {
        red[tid] = umax64(partial[tid], partial[tid + 256]);
        __syncthreads();
        #pragma unroll
        for (int s = 128; s >= 1; s >>= 1) {
            if (tid < s) red[tid] = umax64(red[tid], red[tid + s]);
            __syncthreads();
        }
        int wid = (int)(0xFFFFFFFFu - (unsigned)(red[0] & 0xFFFFFFFFull));
        if (blockIdx.x == 0 && tid == 0) out_cap[t - 1] = (float)wid;
        x = word_emb + (size_t)wid * W_DIM;
    }

    float g[4];
    #pragma unroll
    for (int gi = 0; gi < 4; ++gi) {
        int row = gi * H_DIM + j;
        float acc = lstm_row_dot(W_ih + (size_t)row * W_DIM,
                                 W_hh + (size_t)row * H_DIM, x, h_in, lane);
        g[gi] = acc + b_ih[row] + b_hh[row];
    }
    if (lane == 0) {
        float ig = 1.f / (1.f + expf(-g[0]));
        float fg = 1.f / (1.f + expf(-g[1]));
        float gg = tanhf(g[2]);
        float og = 1.f / (1.f + expf(-g[3]));
        float cn = fg * c_in[j] + ig * gg;
        float hn = og * tanhf(cn);
        c_out[j] = cn;
        h_out[j] = hn;
        if (out_hid) out_hid[j] = hn;
    }
}

__global__ void k_logits_bf16(const ushort* __restrict__ WP16,
                              const float* __restrict__ WP_b,
                              const float* __restrict__ h,
                              unsigned long long* __restrict__ partial) {
    int wave = threadIdx.x >> 6;
    int lane = threadIdx.x & 63;
    int wv = blockIdx.x * 4 + wave;
    float4 h0a = *reinterpret_cast<const float4*>(h + 8 * lane);
    float4 h0b = *reinterpret_cast<const float4*>(h + 8 * lane + 4);
    float4 h1a = *reinterpret_cast<const float4*>(h + 8 * lane + 512);
    float4 h1b = *reinterpret_cast<const float4*>(h + 8 * lane + 516);
    unsigned long long best = 0ull;
    for (int row = wv; row < VOC; row += NBLK_LOGITS * 4) {
        const uint4* wr = reinterpret_cast<const uint4*>(WP16 + (size_t)row * H_DIM);
        uint4 w0 = wr[lane];
        uint4 w1 = wr[lane + 64];
        float acc;
        acc  = bflo(w0.x) * h0a.x + bfhi(w0.x) * h0a.y;
        acc += bflo(w0.y) * h0a.z + bfhi(w0.y) * h0a.w;
        acc += bflo(w0.z) * h0b.x + bfhi(w0.z) * h0b.y;
        acc += bflo(w0.w) * h0b.z + bfhi(w0.w) * h0b.w;
        acc += bflo(w1.x) * h1a.x + bfhi(w1.x) * h1a.y;
        acc += bflo(w1.y) * h1a.z + bfhi(w1.y) * h1a.w;
        acc += bflo(w1.z) * h1b.x + bfhi(w1.z) * h1b.y;
        acc += bflo(w1.w) * h1b.z + bfhi(w1.w) * h1b.w;
        acc = wave_reduce_sum(acc);
        float logit = acc + WP_b[row];
        unsigned int ub = __float_as_uint(logit);
        ub = (ub & 0x80000000u) ? ~ub : (ub | 0x80000000u);
        unsigned long long pk = ((unsigned long long)ub << 32)
                              | (unsigned long long)(0xFFFFFFFFu - (unsigned)row);
        best = umax64(best, pk);
    }
    __shared__ unsigned long long sm[4];
    if (lane == 0) sm[wave] = best;
    __syncthreads();
    if (threadIdx.x == 0)
        partial[blockIdx.x] = umax64(umax64(sm[0], sm[1]), umax64(sm[2], sm[3]));
}

__global__ void k_argmax_final(const unsigned long long* __restrict__ partial,
                               float* __restrict__ out_cap) {
    __shared__ unsigned long long sm[256];
    int tid = threadIdx.x;
    sm[tid] = umax64(partial[tid], partial[tid + 256]);
    __syncthreads();
    for (int s = 128; s > 0; s >>= 1) {
        if (tid < s) sm[tid] = umax64(sm[tid], sm[tid + s]);
        __syncthreads();
    }
    if (tid == 0) {
        int row = (int)(0xFFFFFFFFu - (unsigned)(sm[0] & 0xFFFFFFFFull));
        out_cap[CAP_LEN - 1] = (float)row;
    }
}

extern "C" void kernel_launch(void* const* d_in, const int* in_sizes, int n_in,
                              void* d_out, int out_size, void* d_ws, size_t ws_size,
                              hipStream_t stream) {
    const float* img_feat = (const float*)d_in[0];
    const int*   uid      = (const int*)  d_in[1];
    const float* wei_user = (const float*)d_in[2];
    const float* WI_w     = (const float*)d_in[3];
    const float* WI_b     = (const float*)d_in[4];
    const float* WP_w     = (const float*)d_in[5];
    const float* WP_b     = (const float*)d_in[6];
    const float* W_ih     = (const float*)d_in[7];
    const float* W_hh     = (const float*)d_in[8];
    const float* b_ih     = (const float*)d_in[9];
    const float* b_hh     = (const float*)d_in[10];
    const float* word_emb = (const float*)d_in[11];

    float* out = (float*)d_out;
    float* out_cap = out + CAP_LEN * H_DIM;
    char* ws = (char*)d_ws;

    ushort* WP16 = (ushort*)(ws + (1 << 20));
    const size_t wp16_need = (size_t)(1u << 20) + (size_t)VOC * H_DIM * sizeof(ushort);
    const bool use_bf16 = ws_size >= wp16_need;

    if (use_bf16)
        k_cvt_wp<<<16000, 256, 0, stream>>>(WP_w, WP16);

    k_reset<<<1, 512, 0, stream>>>((unsigned*)ws);

    CoopParams p;
    p.img = img_feat; p.wei_user = wei_user; p.WI_w = WI_w; p.WI_b = WI_b;
    p.WP_w = WP_w; p.WP_b = WP_b; p.W_ih = W_ih; p.W_hh = W_hh;
    p.b_ih = b_ih; p.b_hh = b_hh; p.word_emb = word_emb; p.uid = uid;
    p.WP16 = WP16;
    p.leaf = (unsigned*)ws;
    p.root = (unsigned*)(ws + 1024);
    p.gen  = (unsigned*)(ws + 1152);
    p.h_glob  = (float*)(ws + 2048);
    p.x0_glob = (float*)(ws + 6144);
    p.partial = (unsigned long long*)(ws + 8192);
    p.out_hid = out; p.out_cap = out_cap; p.use_bf16 = use_bf16 ? 1 : 0;

    void* args[] = { &p };
    hipError_t err = hipLaunchCooperativeKernel((const void*)k_decode,
                                                dim3(CO_NBLK), dim3(CO_NTHR),
                                                args, 0, stream);
    if (err != hipSuccess) {
        (void)hipGetLastError();   // clear sticky error, use multi-launch path
        float* wsf = (float*)(ws + 16384);
        float* h0 = wsf;
        float* h1 = wsf + 1024;
        float* c0 = wsf + 2048;
        float* c1 = wsf + 3072;
        float* xin = wsf + 4096;
        float* x0  = wsf + 6400;
        unsigned long long* partial = (unsigned long long*)(ws + 16384 + 27904);
        k_init<<<16, 256, 0, stream>>>(img_feat, uid, wei_user, wsf);
        k_x0<<<128, 256, 0, stream>>>(WI_w, WI_b, xin, x0);
        k_lstm<<<256, 256, 0, stream>>>(-1, W_ih, W_hh, b_ih, b_hh, word_emb, x0,
                                        partial, out_cap, h0, c0, h1, c1, nullptr);
        for (int t = 0; t < CAP_LEN; ++t) {
            const float* hi = (t & 1) ? h0 : h1;
            const float* ci = (t & 1) ? c0 : c1;
            float* ho = (t & 1) ? h1 : h0;
            float* co = (t & 1) ? c1 : c0;
            k_lstm<<<256, 256, 0, stream>>>(t, W_ih, W_hh, b_ih, b_hh, word_emb, x0,
                                            partial, out_cap, hi, ci, ho, co,
                                            out + (size_t)t * H_DIM);
            k_logits_bf16<<<NBLK_LOGITS, 256, 0, stream>>>(WP16, WP_b, ho, partial);
        }
        k_argmax_final<<<1, 256, 0, stream>>>(partial, out_cap);
    }
}